// Round 5
// baseline (283.954 us; speedup 1.0000x reference)
//
#include <hip/hip_runtime.h>
#include <hip/hip_bf16.h>

typedef __attribute__((ext_vector_type(8))) __bf16 bf16x8;
typedef __attribute__((ext_vector_type(4))) __bf16 bf16x4;
typedef __attribute__((ext_vector_type(4))) float f32x4;

#define MFMA(a, b, c) __builtin_amdgcn_mfma_f32_16x16x32_bf16((a), (b), (c), 0, 0, 0)

__device__ __forceinline__ bf16x8 pack8(f32x4 a, f32x4 b) {
    bf16x8 r;
    r[0] = (__bf16)a[0]; r[1] = (__bf16)a[1]; r[2] = (__bf16)a[2]; r[3] = (__bf16)a[3];
    r[4] = (__bf16)b[0]; r[5] = (__bf16)b[1]; r[6] = (__bf16)b[2]; r[7] = (__bf16)b[3];
    return r;
}

__device__ __forceinline__ bf16x8 cvt8(const float* __restrict__ p) {
    return pack8(*(const f32x4*)(p), *(const f32x4*)(p + 4));
}

// ---------------------------------------------------------------------------
// Kernel 1 (transposed): y1 = x @ W1a[0:128,:] + b1a ; y2 = x @ W2a[0:128,:] + b2a
// ---------------------------------------------------------------------------
__global__ __launch_bounds__(256) void precompute_y(
    const float* __restrict__ x,
    const float* __restrict__ W1a, const float* __restrict__ b1a,
    const float* __restrict__ W2a, const float* __restrict__ b2a,
    float* __restrict__ y1, float* __restrict__ y2,
    int N, int ntiles)
{
    const int LDK = 136;                       // 128 + 8 pad
    __shared__ __align__(16) __bf16 w1t[64 * 136];
    __shared__ __align__(16) __bf16 w2t[64 * 136];
    for (int idx = threadIdx.x; idx < 64 * 128; idx += 256) {
        int k = idx >> 6, n = idx & 63;
        w1t[n * LDK + k] = (__bf16)W1a[k * 64 + n];
        w2t[n * LDK + k] = (__bf16)W2a[k * 64 + n];
    }
    __syncthreads();

    const int lane = threadIdx.x & 63, wave = threadIdx.x >> 6;
    const int l15 = lane & 15, l4 = lane >> 4;

    f32x4 bias1[4], bias2[4];
#pragma unroll
    for (int nt = 0; nt < 4; ++nt) {
        bias1[nt] = *(const f32x4*)(b1a + nt * 16 + l4 * 4);
        bias2[nt] = *(const f32x4*)(b2a + nt * 16 + l4 * 4);
    }

    for (int tile = blockIdx.x * 4 + wave; tile < ntiles; tile += gridDim.x * 4) {
        const int node = tile * 16 + l15;
        const int nrow = min(node, N - 1);
        f32x4 acc1[4], acc2[4];
#pragma unroll
        for (int nt = 0; nt < 4; ++nt) {
            acc1[nt] = (f32x4){0.f, 0.f, 0.f, 0.f};
            acc2[nt] = (f32x4){0.f, 0.f, 0.f, 0.f};
        }
#pragma unroll
        for (int j = 0; j < 4; ++j) {
            const int k0 = j * 32 + l4 * 8;
            bf16x8 b = cvt8(x + (size_t)nrow * 128 + k0);     // B = x^T (lane l15 = node)
#pragma unroll
            for (int nt = 0; nt < 4; ++nt) {
                bf16x8 a1 = *(const bf16x8*)(w1t + (nt * 16 + l15) * LDK + k0);  // A = W^T rows
                acc1[nt] = MFMA(a1, b, acc1[nt]);
                bf16x8 a2 = *(const bf16x8*)(w2t + (nt * 16 + l15) * LDK + k0);
                acc2[nt] = MFMA(a2, b, acc2[nt]);
            }
        }
        if (node < N) {
#pragma unroll
            for (int nt = 0; nt < 4; ++nt) {
                f32x4 v1 = acc1[nt] + bias1[nt];
                f32x4 v2 = acc2[nt] + bias2[nt];
                *(f32x4*)(y1 + (size_t)node * 64 + nt * 16 + l4 * 4) = v1;
                *(f32x4*)(y2 + (size_t)node * 64 + nt * 16 + l4 * 4) = v2;
            }
        }
    }
}

// ---------------------------------------------------------------------------
// CSR build: histogram -> single-block scan -> scatter
// ---------------------------------------------------------------------------
__global__ __launch_bounds__(256) void hist_kernel(
    const int* __restrict__ recv, int* __restrict__ cnt, int E)
{
    for (int e = blockIdx.x * blockDim.x + threadIdx.x; e < E;
         e += gridDim.x * blockDim.x)
        atomicAdd(&cnt[recv[e]], 1);
}

__global__ __launch_bounds__(1024) void scan_offsets(
    const int* __restrict__ cnt, int* __restrict__ offs, int* __restrict__ cur, int N)
{
    __shared__ int wsum[16];
    __shared__ int stot;
    const int tid = threadIdx.x;
    const int lane = tid & 63, wave = tid >> 6;
    int carry = 0;
    const int CH = 4096;                       // 1024 threads x 4 elems
    for (int base = 0; base < N; base += CH) {
        const int idx = base + tid * 4;
        int v0 = (idx + 0 < N) ? cnt[idx + 0] : 0;
        int v1 = (idx + 1 < N) ? cnt[idx + 1] : 0;
        int v2 = (idx + 2 < N) ? cnt[idx + 2] : 0;
        int v3 = (idx + 3 < N) ? cnt[idx + 3] : 0;
        const int t = v0 + v1 + v2 + v3;
        int s = t;                              // inclusive wave scan
#pragma unroll
        for (int d = 1; d < 64; d <<= 1) {
            int u = __shfl_up(s, d);
            if (lane >= d) s += u;
        }
        if (lane == 63) wsum[wave] = s;
        __syncthreads();
        if (wave == 0) {
            int w = (lane < 16) ? wsum[lane] : 0;
            int ws = w;
#pragma unroll
            for (int d = 1; d < 16; d <<= 1) {
                int u = __shfl_up(ws, d);
                if (lane >= d) ws += u;
            }
            if (lane < 16) wsum[lane] = ws - w;  // exclusive wave offsets
            if (lane == 15) stot = ws;
        }
        __syncthreads();
        const int excl = s - t + wsum[wave] + carry;
        if (idx + 0 < N) { offs[idx+0] = excl;                cur[idx+0] = excl; }
        if (idx + 1 < N) { offs[idx+1] = excl+v0;             cur[idx+1] = excl+v0; }
        if (idx + 2 < N) { offs[idx+2] = excl+v0+v1;          cur[idx+2] = excl+v0+v1; }
        if (idx + 3 < N) { offs[idx+3] = excl+v0+v1+v2;       cur[idx+3] = excl+v0+v1+v2; }
        carry += stot;
        __syncthreads();                        // protect wsum/stot for next chunk
    }
    if (tid == 0) offs[N] = carry;
}

__global__ __launch_bounds__(256) void scatter_kernel(
    const int* __restrict__ recv, int* __restrict__ cur, int* __restrict__ elist, int E)
{
    for (int e = blockIdx.x * blockDim.x + threadIdx.x; e < E;
         e += gridDim.x * blockDim.x) {
        const int p = atomicAdd(&cur[recv[e]], 1);
        elist[p] = e;
    }
}

// ---------------------------------------------------------------------------
// Fused CSR kernel: each WAVE owns 16 receiver nodes.
//   loop over its contiguous CSR edge range in groups of 32:
//     edge MLP (2 batches of 16, verified round-4 structure) -> msgT in LDS
//     segment-sum via selection-matrix MFMA: agg += S(0/1) @ msg
//   then node MLP on in-register agg -> out.  NO atomics.
// ---------------------------------------------------------------------------
__global__ __launch_bounds__(256) void fused_csr(
    const float* __restrict__ eattr,
    const int* __restrict__ send,
    const int* __restrict__ offs, const int* __restrict__ elist,
    const float* __restrict__ W1a, const float* __restrict__ W1b,
    const float* __restrict__ b1b,
    const float* __restrict__ W2a, const float* __restrict__ W2b,
    const float* __restrict__ b2b,
    const float* __restrict__ y1, const float* __restrict__ y2,
    float* __restrict__ out,
    int N, int E, int ntiles)
{
    const int LDK = 72;                        // 64 + 8 pad
    const int LDE = 40;                        // 32 slots + 8 pad (16B-aligned rows)
    __shared__ __align__(16) __bf16 wat1[64 * 72];  // W1a[128:192,:]^T
    __shared__ __align__(16) __bf16 wbt1[64 * 72];  // W1b^T
    __shared__ __align__(16) __bf16 wat2[64 * 72];  // W2a[128:192,:]^T
    __shared__ __align__(16) __bf16 wbt2[64 * 72];  // W2b^T
    __shared__ __align__(16) __bf16 hbuf[4][16 * 72];
    __shared__ __align__(16) __bf16 msgT[4][64 * 40];
    __shared__ __align__(16) __bf16 aggL[4][16 * 72];

    for (int idx = threadIdx.x; idx < 64 * 64; idx += 256) {
        int k = idx >> 6, n = idx & 63;
        wat1[n * LDK + k] = (__bf16)W1a[(128 + k) * 64 + n];
        wbt1[n * LDK + k] = (__bf16)W1b[k * 64 + n];
        wat2[n * LDK + k] = (__bf16)W2a[(128 + k) * 64 + n];
        wbt2[n * LDK + k] = (__bf16)W2b[k * 64 + n];
    }
    __syncthreads();

    const int lane = threadIdx.x & 63, wave = threadIdx.x >> 6;
    const int l15 = lane & 15, l4 = lane >> 4;
    __bf16* hb = hbuf[wave];
    __bf16* mT = msgT[wave];
    __bf16* aL = aggL[wave];

    float bb1[4];                              // edge layer-2 bias, col = nt*16+l15
    f32x4 bias2b[4];                           // node layer-2 bias (transposed form)
#pragma unroll
    for (int nt = 0; nt < 4; ++nt) {
        bb1[nt] = b1b[nt * 16 + l15];
        bias2b[nt] = *(const f32x4*)(b2b + nt * 16 + l4 * 4);
    }

    for (int tile = blockIdx.x * 4 + wave; tile < ntiles; tile += gridDim.x * 4) {
        const int rbase = tile * 16;
        // CSR boundaries: this lane's receiver row is rbase + l15
        const int oL = offs[min(rbase + l15, N)];
        const int oR = offs[min(rbase + l15 + 1, N)];
        const int segBeg = offs[rbase];
        const int segEnd = offs[min(rbase + 16, N)];

        f32x4 agg[4];
#pragma unroll
        for (int nt = 0; nt < 4; ++nt) agg[nt] = (f32x4){0.f, 0.f, 0.f, 0.f};

        for (int p0 = segBeg; p0 < segEnd; p0 += 32) {
            // ---- edge MLP: 2 batches of 16 edges -> msgT[64 cols][32 slots]
#pragma unroll
            for (int half = 0; half < 2; ++half) {
                const int p = p0 + half * 16 + l15;     // unclamped slot position
                const int e = elist[min(p, E - 1)];     // junk edges masked by S
                const int s = send[e];
                // layer 1 (transposed): C-init = y1[send]
                f32x4 acc[4];
#pragma unroll
                for (int nt = 0; nt < 4; ++nt)
                    acc[nt] = *(const f32x4*)(y1 + (size_t)s * 64 + nt * 16 + l4 * 4);
#pragma unroll
                for (int j = 0; j < 2; ++j) {
                    const int k0 = j * 32 + l4 * 8;
                    bf16x8 b = cvt8(eattr + (size_t)e * 64 + k0);
#pragma unroll
                    for (int nt = 0; nt < 4; ++nt) {
                        bf16x8 a = *(const bf16x8*)(wat1 + (nt * 16 + l15) * LDK + k0);
                        acc[nt] = MFMA(a, b, acc[nt]);
                    }
                }
#pragma unroll
                for (int nt = 0; nt < 4; ++nt) {
                    bf16x4 hv;
#pragma unroll
                    for (int r = 0; r < 4; ++r) hv[r] = (__bf16)fmaxf(acc[nt][r], 0.f);
                    *(bf16x4*)(hb + l15 * LDK + nt * 16 + l4 * 4) = hv;
                }
                // layer 2 (normal): D row = edge slot l4*4+r, col = nt*16+l15
                f32x4 acc2[4];
#pragma unroll
                for (int nt = 0; nt < 4; ++nt)
                    acc2[nt] = (f32x4){bb1[nt], bb1[nt], bb1[nt], bb1[nt]};
#pragma unroll
                for (int j = 0; j < 2; ++j) {
                    const int k0 = j * 32 + l4 * 8;
                    bf16x8 hfrag = *(const bf16x8*)(hb + l15 * LDK + k0);
#pragma unroll
                    for (int nt = 0; nt < 4; ++nt) {
                        bf16x8 w = *(const bf16x8*)(wbt1 + (nt * 16 + l15) * LDK + k0);
                        acc2[nt] = MFMA(hfrag, w, acc2[nt]);
                    }
                }
#pragma unroll
                for (int nt = 0; nt < 4; ++nt) {
                    bf16x4 mv;
#pragma unroll
                    for (int r = 0; r < 4; ++r) mv[r] = (__bf16)fmaxf(acc2[nt][r], 0.f);
                    *(bf16x4*)(mT + (nt * 16 + l15) * LDE + half * 16 + l4 * 4) = mv;
                }
            }
            // ---- selection fragment S[row l15][k = l4*8+i] (bf16 0/1 exact)
            bf16x8 sf;
#pragma unroll
            for (int i = 0; i < 8; ++i) {
                const int p = p0 + l4 * 8 + i;
                sf[i] = (__bf16)((p >= oL && p < oR) ? 1.f : 0.f);
            }
            // ---- segment-sum MFMA: agg[recv rows] += S @ msg
#pragma unroll
            for (int nt = 0; nt < 4; ++nt) {
                bf16x8 m = *(const bf16x8*)(mT + (nt * 16 + l15) * LDE + l4 * 8);
                agg[nt] = MFMA(sf, m, agg[nt]);
            }
        }

        // ---- stage agg (D layout: row=l4*4+r, col=nt*16+l15) row-major into LDS
#pragma unroll
        for (int nt = 0; nt < 4; ++nt)
#pragma unroll
            for (int r = 0; r < 4; ++r)
                aL[(l4 * 4 + r) * LDK + nt * 16 + l15] = (__bf16)agg[nt][r];

        // ---- node MLP (transposed, lane l15 = node row in tile)
        const int node = rbase + l15;
        const int nrow = min(node, N - 1);
        f32x4 acc[4];
#pragma unroll
        for (int nt = 0; nt < 4; ++nt)
            acc[nt] = *(const f32x4*)(y2 + (size_t)nrow * 64 + nt * 16 + l4 * 4);
#pragma unroll
        for (int j = 0; j < 2; ++j) {
            const int k0 = j * 32 + l4 * 8;
            bf16x8 b = *(const bf16x8*)(aL + l15 * LDK + k0);
#pragma unroll
            for (int nt = 0; nt < 4; ++nt) {
                bf16x8 a = *(const bf16x8*)(wat2 + (nt * 16 + l15) * LDK + k0);
                acc[nt] = MFMA(a, b, acc[nt]);
            }
        }
#pragma unroll
        for (int nt = 0; nt < 4; ++nt) {
            bf16x4 hv;
#pragma unroll
            for (int r = 0; r < 4; ++r) hv[r] = (__bf16)fmaxf(acc[nt][r], 0.f);
            *(bf16x4*)(hb + l15 * LDK + nt * 16 + l4 * 4) = hv;
        }
        f32x4 acc2[4];
#pragma unroll
        for (int nt = 0; nt < 4; ++nt) acc2[nt] = bias2b[nt];
#pragma unroll
        for (int j = 0; j < 2; ++j) {
            const int k0 = j * 32 + l4 * 8;
            bf16x8 b = *(const bf16x8*)(hb + l15 * LDK + k0);
#pragma unroll
            for (int nt = 0; nt < 4; ++nt) {
                bf16x8 a = *(const bf16x8*)(wbt2 + (nt * 16 + l15) * LDK + k0);
                acc2[nt] = MFMA(a, b, acc2[nt]);
            }
        }
        if (node < N) {
#pragma unroll
            for (int nt = 0; nt < 4; ++nt) {
                f32x4 v;
#pragma unroll
                for (int r = 0; r < 4; ++r) v[r] = fmaxf(acc2[nt][r], 0.f);
                *(f32x4*)(out + (size_t)node * 64 + nt * 16 + l4 * 4) = v;
            }
        }
    }
}

// ---------------------------------------------------------------------------
extern "C" void kernel_launch(void* const* d_in, const int* in_sizes, int n_in,
                              void* d_out, int out_size, void* d_ws, size_t ws_size,
                              hipStream_t stream) {
    const float* x     = (const float*)d_in[0];
    const int*   eidx  = (const int*)d_in[1];
    const float* eattr = (const float*)d_in[2];
    // d_in[3] = u (unused), d_in[4] = batch (unused)
    const float* W1a = (const float*)d_in[5];
    const float* b1a = (const float*)d_in[6];
    const float* W1b = (const float*)d_in[7];
    const float* b1b = (const float*)d_in[8];
    const float* W2a = (const float*)d_in[9];
    const float* b2a = (const float*)d_in[10];
    const float* W2b = (const float*)d_in[11];
    const float* b2b = (const float*)d_in[12];
    float* out = (float*)d_out;

    const int N = in_sizes[0] / 128;
    const int E = in_sizes[1] / 2;
    const int* send = eidx;
    const int* recv = eidx + E;

    const size_t NG = (size_t)N * 64;
    float* y1   = (float*)d_ws;
    float* y2   = y1 + NG;
    int*   cnt  = (int*)(y2 + NG);
    int*   offs = cnt + (N + 1);
    int*   cur  = offs + (N + 1);
    int*   elist = cur + N;

    hipMemsetAsync(cnt, 0, (size_t)(N + 1) * sizeof(int), stream);

    const int ntilesN = (N + 15) / 16;
    int blkN = (ntilesN + 3) / 4;
    if (blkN > 2048) blkN = 2048;
    int blkS = (E + 255) / 256;
    if (blkS > 2048) blkS = 2048;

    precompute_y<<<blkN, 256, 0, stream>>>(x, W1a, b1a, W2a, b2a, y1, y2, N, ntilesN);
    hist_kernel<<<blkS, 256, 0, stream>>>(recv, cnt, E);
    scan_offsets<<<1, 1024, 0, stream>>>(cnt, offs, cur, N);
    scatter_kernel<<<blkS, 256, 0, stream>>>(recv, cur, elist, E);
    fused_csr<<<blkN, 256, 0, stream>>>(eattr, send, offs, elist,
                                        W1a, W1b, b1b, W2a, W2b, b2b,
                                        y1, y2, out, N, E, ntilesN);
}